// Round 1
// baseline (19424.892 us; speedup 1.0000x reference)
//
#include <hip/hip_runtime.h>
#include <hip/hip_bf16.h>

typedef __attribute__((ext_vector_type(8))) short bf16x8;
typedef __attribute__((ext_vector_type(4))) float f32x4;
typedef unsigned short u16;
typedef unsigned int u32;

#define DEVFN __device__ __forceinline__

constexpr int B_ = 16, S_ = 1024, H_ = 1024, NSP = 32;
constexpr int G4 = 4 * H_;     // 4096 gate columns
constexpr int NWG = 256;       // persistent LSTM workgroups (one per CU)

DEVFN u16 f2bf(float f) {
  __hip_bfloat16 h = __float2bfloat16(f);
  return *reinterpret_cast<u16*>(&h);
}
DEVFN float bf2f(u16 u) {
  u32 x = ((u32)u) << 16;
  float f;
  __builtin_memcpy(&f, &x, 4);
  return f;
}

// ---------------- prep kernels ----------------

// x [B][S][H] f32 -> xT [S][B][H] bf16
__global__ void k_prep_x(const float* __restrict__ x, u16* __restrict__ xT) {
  int id = blockIdx.x * 256 + threadIdx.x;   // 0 .. B*S*H/4-1
  int k4 = id & 255;
  int b = (id >> 8) & 15;
  int s = id >> 12;
  float4 v = *reinterpret_cast<const float4*>(x + (size_t)(b * S_ + s) * H_ + k4 * 4);
  ushort4 o;
  o.x = f2bf(v.x); o.y = f2bf(v.y); o.z = f2bf(v.z); o.w = f2bf(v.w);
  *reinterpret_cast<ushort4*>(xT + (size_t)(s * B_ + b) * H_ + k4 * 4) = o;
}

// convert Wq/Wk/Wv/Wo to bf16 (plain [N][K]); bias4 = b_ih + b_hh
__global__ void k_prep_small(const float* __restrict__ Wq, const float* __restrict__ Wk,
                             const float* __restrict__ Wv, const float* __restrict__ Wo,
                             u16* __restrict__ Wqb, u16* __restrict__ Wkb,
                             u16* __restrict__ Wvb, u16* __restrict__ Wob,
                             const float* __restrict__ bih, const float* __restrict__ bhh,
                             float* __restrict__ bias4) {
  int id = blockIdx.x * 256 + threadIdx.x;
  if (id < 4 * H_ * H_) {
    int which = id >> 20;
    int r = id & (H_ * H_ - 1);
    const float* src = which == 0 ? Wq : which == 1 ? Wk : which == 2 ? Wv : Wo;
    u16* dst = which == 0 ? Wqb : which == 1 ? Wkb : which == 2 ? Wvb : Wob;
    dst[r] = f2bf(src[r]);
  } else {
    int r = id - 4 * H_ * H_;
    if (r < G4) bias4[r] = bih[r] + bhh[r];
  }
}

// pack W_ih/W_hh into per-WG MFMA A-fragment blocks.
// WG p, A-tile row j (0..15): unit = j>>2, gate = j&3  ->  W row = gate*1024 + p*4 + unit.
// Fragment: lane l holds row (l&15), k = (l>>4)*8 + e.  Block layout (16B units): [part][c][l].
__global__ void k_prep_wpack(const float* __restrict__ Wih, const float* __restrict__ Whh,
                             u16* __restrict__ Wpk) {
  int g = blockIdx.x * 256 + threadIdx.x;   // 0..1048575
  int p = g >> 12;
  int rem = g & 4095;
  int part = rem >> 11;
  int c = (rem >> 6) & 31;
  int l = rem & 63;
  int j = l & 15;
  int row = (j & 3) * H_ + p * 4 + (j >> 2);
  int kb = c * 32 + (l >> 4) * 8;
  const float* src = (part ? Whh : Wih) + (size_t)row * H_ + kb;
  alignas(16) u16 o[8];
#pragma unroll
  for (int e = 0; e < 8; ++e) o[e] = f2bf(src[e]);
  *reinterpret_cast<uint4*>(Wpk + (size_t)g * 8) = *reinterpret_cast<const uint4*>(o);
}

// ---------------- persistent LSTM ----------------

struct Bar {
  u32 cnt;
  u32 pad0[31];
  u32 epoch;
  u32 pad1[31];
};

__launch_bounds__(64, 1)
__global__ void k_lstm(const u16* __restrict__ xT, const u16* __restrict__ Wpk,
                       const float* __restrict__ bias4,
                       const int* __restrict__ head, const int* __restrict__ tail,
                       u16* __restrict__ hbuf, float* __restrict__ spanacc,
                       Bar* __restrict__ bar) {
  __shared__ __align__(16) u16 wlds[32768];   // 64 KiB: [part(2)][c(32)][l(64)][e(8)] bf16
  const int p = blockIdx.x;
  const int l = threadIdx.x;
  const int bb = l & 15;    // batch
  const int q = l >> 4;     // unit 0..3 within this WG

  {  // stage weight slice once
    const uint4* wg = reinterpret_cast<const uint4*>(Wpk + (size_t)p * 32768);
    uint4* wl = reinterpret_cast<uint4*>(wlds);
#pragma unroll
    for (int i = 0; i < 64; ++i) wl[i * 64 + l] = wg[i * 64 + l];
  }
  float bias_g[4];
#pragma unroll
  for (int r = 0; r < 4; ++r) bias_g[r] = bias4[r * H_ + p * 4 + q];
  int hd[NSP], tl[NSP];
#pragma unroll
  for (int n = 0; n < NSP; ++n) {
    hd[n] = head[bb * NSP + n];
    tl[n] = tail[bb * NSP + n];
  }
  float aspan[NSP];
#pragma unroll
  for (int n = 0; n < NSP; ++n) aspan[n] = 0.f;
  float creg = 0.f;
  __syncthreads();

  const bf16x8* wfrag = reinterpret_cast<const bf16x8*>(wlds);
  const int boff = bb * H_ + q * 8;

  for (int t = 0; t < S_; ++t) {
    const u16* xrow = xT + (size_t)t * (B_ * H_);
    const u16* hrow = hbuf + (size_t)(t & 1) * (B_ * H_);
    f32x4 acc = {0.f, 0.f, 0.f, 0.f};
#pragma unroll 8
    for (int c = 0; c < 32; ++c) {  // x @ W_ih^T
      bf16x8 bv = *reinterpret_cast<const bf16x8*>(xrow + boff + c * 32);
      acc = __builtin_amdgcn_mfma_f32_16x16x32_bf16(wfrag[c * 64 + l], bv, acc, 0, 0, 0);
    }
#pragma unroll 8
    for (int c = 0; c < 32; ++c) {  // h @ W_hh^T
      bf16x8 bv = *reinterpret_cast<const bf16x8*>(hrow + boff + c * 32);
      acc = __builtin_amdgcn_mfma_f32_16x16x32_bf16(wfrag[2048 + c * 64 + l], bv, acc, 0, 0, 0);
    }
    // lane (bb, q) holds its own i,f,g,o in acc[0..3]
    float gi = acc[0] + bias_g[0];
    float gf = acc[1] + bias_g[1];
    float gg = acc[2] + bias_g[2];
    float go = acc[3] + bias_g[3];
    float si = 1.f / (1.f + __expf(-gi));
    float sf = 1.f / (1.f + __expf(-gf));
    float tg = tanhf(gg);
    float so = 1.f / (1.f + __expf(-go));
    creg = sf * creg + si * tg;
    float hval = so * tanhf(creg);
    hbuf[(size_t)((t + 1) & 1) * (B_ * H_) + bb * H_ + p * 4 + q] = f2bf(hval);
#pragma unroll
    for (int n = 0; n < NSP; ++n)
      if (t >= hd[n] + 1 && t < tl[n]) aspan[n] += hval;

    // device-wide barrier (sense via monotonically increasing epoch)
    __threadfence();
    if (l == 0) {
      u32 target = (u32)(t + 1);
      u32 old = __hip_atomic_fetch_add(&bar->cnt, 1u, __ATOMIC_ACQ_REL, __HIP_MEMORY_SCOPE_AGENT);
      if (old == (u32)(NWG - 1)) {
        __hip_atomic_store(&bar->cnt, 0u, __ATOMIC_RELAXED, __HIP_MEMORY_SCOPE_AGENT);
        __hip_atomic_store(&bar->epoch, target, __ATOMIC_RELEASE, __HIP_MEMORY_SCOPE_AGENT);
      } else {
        while (__hip_atomic_load(&bar->epoch, __ATOMIC_RELAXED, __HIP_MEMORY_SCOPE_AGENT) < target)
          __builtin_amdgcn_s_sleep(4);
      }
    }
    __threadfence();
  }
#pragma unroll
  for (int n = 0; n < NSP; ++n)
    spanacc[(size_t)(bb * NSP + n) * H_ + p * 4 + q] = aspan[n];
}

// ---------------- small GEMM: C[M,N] = A[M,K] @ Bw[N,K]^T + bias ----------------

__launch_bounds__(256, 2)
__global__ void k_gemm(const u16* __restrict__ A, const u16* __restrict__ Bw,
                       const float* __restrict__ bias, float* __restrict__ C,
                       int M, int N, int K) {
  __shared__ __align__(16) u16 As[64][40];
  __shared__ __align__(16) u16 Bs[64][40];
  const int bm = blockIdx.y * 64, bn = blockIdx.x * 64;
  const int tid = threadIdx.x;
  const int w = tid >> 6, l = tid & 63;
  const int sr = tid >> 2, sc = (tid & 3) * 8;
  f32x4 acc[4];
#pragma unroll
  for (int j = 0; j < 4; ++j) acc[j] = (f32x4){0.f, 0.f, 0.f, 0.f};
  for (int k0 = 0; k0 < K; k0 += 32) {
    *reinterpret_cast<uint4*>(&As[sr][sc]) =
        *reinterpret_cast<const uint4*>(A + (size_t)(bm + sr) * K + k0 + sc);
    *reinterpret_cast<uint4*>(&Bs[sr][sc]) =
        *reinterpret_cast<const uint4*>(Bw + (size_t)(bn + sr) * K + k0 + sc);
    __syncthreads();
    bf16x8 af = *reinterpret_cast<const bf16x8*>(&As[w * 16 + (l & 15)][(l >> 4) * 8]);
#pragma unroll
    for (int j = 0; j < 4; ++j) {
      bf16x8 bf_ = *reinterpret_cast<const bf16x8*>(&Bs[j * 16 + (l & 15)][(l >> 4) * 8]);
      acc[j] = __builtin_amdgcn_mfma_f32_16x16x32_bf16(af, bf_, acc[j], 0, 0, 0);
    }
    __syncthreads();
  }
#pragma unroll
  for (int j = 0; j < 4; ++j) {
    int col = bn + j * 16 + (l & 15);
    float bv = bias ? bias[col] : 0.f;
#pragma unroll
    for (int r = 0; r < 4; ++r) {
      int row = bm + w * 16 + (l >> 4) * 4 + r;
      C[(size_t)row * N + col] = acc[j][r] + bv;
    }
  }
}

// ---------------- LayerNorm kernels ----------------

DEVFN float blk_reduce(float v, float* lds) {
#pragma unroll
  for (int k = 32; k >= 1; k >>= 1) v += __shfl_xor(v, k, 64);
  __syncthreads();
  if ((threadIdx.x & 63) == 0) lds[threadIdx.x >> 6] = v;
  __syncthreads();
  return lds[0] + lds[1] + lds[2] + lds[3];
}

__global__ void k_ln1(const float* __restrict__ acc, const int* __restrict__ head,
                      const int* __restrict__ tail, const float* __restrict__ g,
                      const float* __restrict__ bta, float* __restrict__ xo,
                      u16* __restrict__ xb) {
  __shared__ float lds[4];
  int m = blockIdx.x, tid = threadIdx.x;
  int hd = head[m], tl = tail[m];
  int lo = hd + 1 > 0 ? hd + 1 : 0;
  int hi = tl < S_ ? tl : S_;
  float cnt = (float)(hi - lo > 0 ? hi - lo : 0);
  if (cnt < 1.f) cnt = 1.f;
  float inv = 1.f / cnt;
  float4 v = reinterpret_cast<const float4*>(acc + (size_t)m * H_)[tid];
  v.x *= inv; v.y *= inv; v.z *= inv; v.w *= inv;
  float s = blk_reduce(v.x + v.y + v.z + v.w, lds);
  float mean = s * (1.f / H_);
  float dx = v.x - mean, dy = v.y - mean, dz = v.z - mean, dw = v.w - mean;
  float ss = blk_reduce(dx * dx + dy * dy + dz * dz + dw * dw, lds);
  float rstd = 1.f / sqrtf(ss * (1.f / H_) + 1e-7f);
  int k = tid * 4;
  float o0 = dx * rstd * g[k + 0] + bta[k + 0];
  float o1 = dy * rstd * g[k + 1] + bta[k + 1];
  float o2 = dz * rstd * g[k + 2] + bta[k + 2];
  float o3 = dw * rstd * g[k + 3] + bta[k + 3];
  float4 ov = {o0, o1, o2, o3};
  reinterpret_cast<float4*>(xo + (size_t)m * H_)[tid] = ov;
  ushort4 ob;
  ob.x = f2bf(o0); ob.y = f2bf(o1); ob.z = f2bf(o2); ob.w = f2bf(o3);
  reinterpret_cast<ushort4*>(xb + (size_t)m * H_)[tid] = ob;
}

__global__ void k_ln2(const float* __restrict__ oo, const float* __restrict__ xres,
                      const float* __restrict__ g, const float* __restrict__ bta,
                      u16* __restrict__ ao) {
  __shared__ float lds[4];
  int m = blockIdx.x, tid = threadIdx.x;
  float4 a = reinterpret_cast<const float4*>(oo + (size_t)m * H_)[tid];
  float4 r = reinterpret_cast<const float4*>(xres + (size_t)m * H_)[tid];
  float4 v = {a.x + r.x, a.y + r.y, a.z + r.z, a.w + r.w};
  float s = blk_reduce(v.x + v.y + v.z + v.w, lds);
  float mean = s * (1.f / H_);
  float dx = v.x - mean, dy = v.y - mean, dz = v.z - mean, dw = v.w - mean;
  float ss = blk_reduce(dx * dx + dy * dy + dz * dz + dw * dw, lds);
  float rstd = 1.f / sqrtf(ss * (1.f / H_) + 1e-7f);
  int k = tid * 4;
  ushort4 ob;
  ob.x = f2bf(dx * rstd * g[k + 0] + bta[k + 0]);
  ob.y = f2bf(dy * rstd * g[k + 1] + bta[k + 1]);
  ob.z = f2bf(dz * rstd * g[k + 2] + bta[k + 2]);
  ob.w = f2bf(dw * rstd * g[k + 3] + bta[k + 3]);
  reinterpret_cast<ushort4*>(ao + (size_t)m * H_)[tid] = ob;
}

// ---------------- attention over spans (32x32 per (b,head)) ----------------

__launch_bounds__(256, 2)
__global__ void k_attn(const float* __restrict__ qf, const float* __restrict__ kf,
                       const float* __restrict__ vf, const int* __restrict__ am,
                       u16* __restrict__ ctx) {
  __shared__ float qs[32][65], ks[32][65], vs[32][65];
  __shared__ float ps[32][33];
  __shared__ int msk[32];
  int blk = blockIdx.x;
  int b = blk >> 4, hh = blk & 15;
  int tid = threadIdx.x;
  for (int i = tid; i < 32 * 64; i += 256) {
    int n = i >> 6, d = i & 63;
    size_t src = (size_t)(b * 32 + n) * H_ + hh * 64 + d;
    qs[n][d] = qf[src];
    ks[n][d] = kf[src];
    vs[n][d] = vf[src];
  }
  if (tid < 32) msk[tid] = am[b * 32 + tid];
  __syncthreads();
  for (int pr = tid; pr < 1024; pr += 256) {
    int i = pr >> 5, j = pr & 31;
    float s = 0.f;
#pragma unroll
    for (int d = 0; d < 64; ++d) s += qs[i][d] * ks[j][d];
    s *= 0.125f;
    if (!(msk[i] && msk[j])) s = -3.402823466e38f;
    ps[i][j] = s;
  }
  __syncthreads();
  if (tid < 32) {
    int i = tid;
    float mx = -3.402823466e38f;
#pragma unroll
    for (int j = 0; j < 32; ++j) mx = fmaxf(mx, ps[i][j]);
    float e[32];
    float sum = 0.f;
#pragma unroll
    for (int j = 0; j < 32; ++j) {
      e[j] = __expf(ps[i][j] - mx);
      sum += e[j];
    }
    float invs = 1.f / sum;
#pragma unroll
    for (int j = 0; j < 32; ++j) ps[i][j] = e[j] * invs;
  }
  __syncthreads();
  for (int o = tid; o < 32 * 64; o += 256) {
    int i = o >> 6, d = o & 63;
    float s = 0.f;
#pragma unroll
    for (int j = 0; j < 32; ++j) s += ps[i][j] * vs[j][d];
    ctx[(size_t)(b * 32 + i) * H_ + hh * 64 + d] = f2bf(s);
  }
}

// ---------------- classifier head ----------------

__global__ void k_cls(const u16* __restrict__ ao, const float* __restrict__ Wc,
                      const float* __restrict__ bc, float* __restrict__ out) {
  int m = blockIdx.x, lane = threadIdx.x;
#pragma unroll
  for (int c = 0; c < 3; ++c) {
    float s = 0.f;
    for (int k = lane; k < H_; k += 64) s += bf2f(ao[(size_t)m * H_ + k]) * Wc[c * H_ + k];
#pragma unroll
    for (int k = 32; k >= 1; k >>= 1) s += __shfl_xor(s, k, 64);
    if (lane == 0) out[m * 3 + c] = s + bc[c];
  }
}

// ---------------- host launcher ----------------

extern "C" void kernel_launch(void* const* d_in, const int* in_sizes, int n_in,
                              void* d_out, int out_size, void* d_ws, size_t ws_size,
                              hipStream_t stream) {
  const float* x = (const float*)d_in[0];
  const int* head = (const int*)d_in[1];
  const int* tail = (const int*)d_in[2];
  const int* amask = (const int*)d_in[3];
  const float* Wih = (const float*)d_in[4];
  const float* Whh = (const float*)d_in[5];
  const float* bih = (const float*)d_in[6];
  const float* bhh = (const float*)d_in[7];
  const float* lng = (const float*)d_in[8];
  const float* lnb = (const float*)d_in[9];
  const float* Wq = (const float*)d_in[10];
  const float* bq = (const float*)d_in[11];
  const float* Wk = (const float*)d_in[12];
  const float* bk = (const float*)d_in[13];
  const float* Wv = (const float*)d_in[14];
  const float* bv = (const float*)d_in[15];
  const float* Wo = (const float*)d_in[16];
  const float* bo = (const float*)d_in[17];
  const float* ln2g = (const float*)d_in[18];
  const float* ln2b = (const float*)d_in[19];
  const float* Wc = (const float*)d_in[20];
  const float* bc = (const float*)d_in[21];
  float* out = (float*)d_out;

  char* wsb = (char*)d_ws;
  size_t off = 0;
  auto alloc = [&](size_t bytes) -> void* {
    void* pp = wsb + off;
    off = (off + bytes + 255) & ~(size_t)255;
    return pp;
  };
  u16* xT = (u16*)alloc((size_t)S_ * B_ * H_ * 2);          // 32 MB
  u16* Wpk = (u16*)alloc((size_t)NWG * 32768 * 2);          // 16 MB
  u16* Wqb = (u16*)alloc((size_t)H_ * H_ * 2);
  u16* Wkb = (u16*)alloc((size_t)H_ * H_ * 2);
  u16* Wvb = (u16*)alloc((size_t)H_ * H_ * 2);
  u16* Wob = (u16*)alloc((size_t)H_ * H_ * 2);
  float* bias4 = (float*)alloc((size_t)G4 * 4);
  u16* hbuf = (u16*)alloc((size_t)2 * B_ * H_ * 2);
  Bar* bar = (Bar*)alloc(sizeof(Bar));
  float* spanacc = (float*)alloc((size_t)B_ * NSP * H_ * 4);
  float* xo = (float*)alloc((size_t)512 * H_ * 4);
  u16* xb = (u16*)alloc((size_t)512 * H_ * 2);
  float* qf = (float*)alloc((size_t)512 * H_ * 4);
  float* kf = (float*)alloc((size_t)512 * H_ * 4);
  float* vf = (float*)alloc((size_t)512 * H_ * 4);
  u16* ctx = (u16*)alloc((size_t)512 * H_ * 2);
  float* oo = (float*)alloc((size_t)512 * H_ * 4);
  u16* ao = (u16*)alloc((size_t)512 * H_ * 2);
  (void)ws_size; (void)in_sizes; (void)n_in; (void)out_size;

  hipMemsetAsync(bar, 0, sizeof(Bar), stream);
  hipMemsetAsync(hbuf, 0, (size_t)2 * B_ * H_ * 2, stream);

  k_prep_x<<<16384, 256, 0, stream>>>(x, xT);
  k_prep_small<<<16400, 256, 0, stream>>>(Wq, Wk, Wv, Wo, Wqb, Wkb, Wvb, Wob, bih, bhh, bias4);
  k_prep_wpack<<<4096, 256, 0, stream>>>(Wih, Whh, Wpk);

  k_lstm<<<NWG, 64, 0, stream>>>(xT, Wpk, bias4, head, tail, hbuf, spanacc, bar);

  k_ln1<<<512, 256, 0, stream>>>(spanacc, head, tail, lng, lnb, xo, xb);
  dim3 g1(16, 8);
  k_gemm<<<g1, 256, 0, stream>>>(xb, Wqb, bq, qf, 512, H_, H_);
  k_gemm<<<g1, 256, 0, stream>>>(xb, Wkb, bk, kf, 512, H_, H_);
  k_gemm<<<g1, 256, 0, stream>>>(xb, Wvb, bv, vf, 512, H_, H_);
  k_attn<<<256, 256, 0, stream>>>(qf, kf, vf, amask, ctx);
  k_gemm<<<g1, 256, 0, stream>>>(ctx, Wob, bo, oo, 512, H_, H_);
  k_ln2<<<512, 256, 0, stream>>>(oo, xo, ln2g, ln2b, ao);
  k_cls<<<512, 64, 0, stream>>>(ao, Wc, bc, out);
}

// Round 2
// 5895.891 us; speedup vs baseline: 3.2946x; 3.2946x over previous
//
#include <hip/hip_runtime.h>
#include <hip/hip_bf16.h>

typedef __attribute__((ext_vector_type(8))) short bf16x8;
typedef __attribute__((ext_vector_type(4))) float f32x4;
typedef unsigned short u16;
typedef unsigned int u32;
typedef unsigned long long u64;

#define DEVFN __device__ __forceinline__

constexpr int B_ = 16, S_ = 1024, H_ = 1024, NSP = 32;
constexpr int G4 = 4 * H_;     // 4096 gate columns
constexpr int NWG = 256;       // persistent LSTM workgroups (one per CU)

DEVFN u16 f2bf(float f) {
  __hip_bfloat16 h = __float2bfloat16(f);
  return *reinterpret_cast<u16*>(&h);
}
DEVFN float bf2f(u16 u) {
  u32 x = ((u32)u) << 16;
  float f;
  __builtin_memcpy(&f, &x, 4);
  return f;
}

// ---------------- prep kernels ----------------

// x [B][S][H] f32 -> xT [S][B][H] bf16
__global__ void k_prep_x(const float* __restrict__ x, u16* __restrict__ xT) {
  int id = blockIdx.x * 256 + threadIdx.x;   // 0 .. B*S*H/4-1
  int k4 = id & 255;
  int b = (id >> 8) & 15;
  int s = id >> 12;
  float4 v = *reinterpret_cast<const float4*>(x + (size_t)(b * S_ + s) * H_ + k4 * 4);
  ushort4 o;
  o.x = f2bf(v.x); o.y = f2bf(v.y); o.z = f2bf(v.z); o.w = f2bf(v.w);
  *reinterpret_cast<ushort4*>(xT + (size_t)(s * B_ + b) * H_ + k4 * 4) = o;
}

// convert Wq/Wk/Wv/Wo to bf16 (plain [N][K]); bias4 = b_ih + b_hh
__global__ void k_prep_small(const float* __restrict__ Wq, const float* __restrict__ Wk,
                             const float* __restrict__ Wv, const float* __restrict__ Wo,
                             u16* __restrict__ Wqb, u16* __restrict__ Wkb,
                             u16* __restrict__ Wvb, u16* __restrict__ Wob,
                             const float* __restrict__ bih, const float* __restrict__ bhh,
                             float* __restrict__ bias4) {
  int id = blockIdx.x * 256 + threadIdx.x;
  if (id < 4 * H_ * H_) {
    int which = id >> 20;
    int r = id & (H_ * H_ - 1);
    const float* src = which == 0 ? Wq : which == 1 ? Wk : which == 2 ? Wv : Wo;
    u16* dst = which == 0 ? Wqb : which == 1 ? Wkb : which == 2 ? Wvb : Wob;
    dst[r] = f2bf(src[r]);
  } else {
    int r = id - 4 * H_ * H_;
    if (r < G4) bias4[r] = bih[r] + bhh[r];
  }
}

// pack W_ih/W_hh into per-WG MFMA A-fragment blocks.
// WG p, A-tile row j (0..15): unit = j>>2, gate = j&3  ->  W row = gate*1024 + p*4 + unit.
// Fragment: lane l holds row (l&15), k = (l>>4)*8 + e.  Block layout (16B units): [part][c][l].
__global__ void k_prep_wpack(const float* __restrict__ Wih, const float* __restrict__ Whh,
                             u16* __restrict__ Wpk) {
  int g = blockIdx.x * 256 + threadIdx.x;   // 0..1048575
  int p = g >> 12;
  int rem = g & 4095;
  int part = rem >> 11;
  int c = (rem >> 6) & 31;
  int l = rem & 63;
  int j = l & 15;
  int row = (j & 3) * H_ + p * 4 + (j >> 2);
  int kb = c * 32 + (l >> 4) * 8;
  const float* src = (part ? Whh : Wih) + (size_t)row * H_ + kb;
  alignas(16) u16 o[8];
#pragma unroll
  for (int e = 0; e < 8; ++e) o[e] = f2bf(src[e]);
  *reinterpret_cast<uint4*>(Wpk + (size_t)g * 8) = *reinterpret_cast<const uint4*>(o);
}

// ---------------- persistent LSTM ----------------
// Sync protocol (per step t):
//   - x-part MFMAs first (no h dependency) to overlap with other WGs' h stores
//   - wave-parallel poll of 256 distributed per-WG flags (agent-scope relaxed
//     atomic loads -> LLC; 4 per lane, one round trip per iteration)
//   - h-part reads row t of a FULL-HISTORY h buffer with PLAIN cached loads
//     (fresh address every step -> no stale L2 copies possible; L2 multicast
//     serves 31 of 32 WGs per XCD)
//   - h stores for row t+1 are agent-scope (sc1, write-through to LLC),
//     16 lanes x 8B per WG; s_waitcnt vmcnt(0); then flag[wg] = t+1.
// No __threadfence (no L2 writeback/invalidate ops), no WAR hazard (fresh rows).

DEVFN u32 ldflag(const u32* f) {
  return __hip_atomic_load(f, __ATOMIC_RELAXED, __HIP_MEMORY_SCOPE_AGENT);
}

__launch_bounds__(64, 1)
__global__ void k_lstm(const u16* __restrict__ xT, const u16* __restrict__ Wpk,
                       const float* __restrict__ bias4,
                       const int* __restrict__ head, const int* __restrict__ tail,
                       u16* __restrict__ hbuf, u32* __restrict__ flags,
                       float* __restrict__ spanacc) {
  __shared__ __align__(16) u16 wlds[32768];   // 64 KiB: [part(2)][c(32)][l(64)][e(8)] bf16
  const int p = blockIdx.x;
  const int l = threadIdx.x;
  const int bb = l & 15;    // batch
  const int q = l >> 4;     // unit 0..3 within this WG

  {  // stage weight slice once
    const uint4* wg = reinterpret_cast<const uint4*>(Wpk + (size_t)p * 32768);
    uint4* wl = reinterpret_cast<uint4*>(wlds);
#pragma unroll
    for (int i = 0; i < 64; ++i) wl[i * 64 + l] = wg[i * 64 + l];
  }
  float bias_g[4];
#pragma unroll
  for (int r = 0; r < 4; ++r) bias_g[r] = bias4[r * H_ + p * 4 + q];
  int hd[NSP], tl[NSP];
#pragma unroll
  for (int n = 0; n < NSP; ++n) {
    hd[n] = head[bb * NSP + n];
    tl[n] = tail[bb * NSP + n];
  }
  float aspan[NSP];
#pragma unroll
  for (int n = 0; n < NSP; ++n) aspan[n] = 0.f;
  float creg = 0.f;
  __syncthreads();

  const bf16x8* wfrag = reinterpret_cast<const bf16x8*>(wlds);
  const int boff = bb * H_ + q * 8;

  for (int t = 0; t < S_; ++t) {
    const u16* xrow = xT + (size_t)t * (B_ * H_);
    const u16* hrow = hbuf + (size_t)t * (B_ * H_);
    f32x4 acc = {0.f, 0.f, 0.f, 0.f};
#pragma unroll 8
    for (int c = 0; c < 32; ++c) {  // x @ W_ih^T  (independent of h)
      bf16x8 bv = *reinterpret_cast<const bf16x8*>(xrow + boff + c * 32);
      acc = __builtin_amdgcn_mfma_f32_16x16x32_bf16(wfrag[c * 64 + l], bv, acc, 0, 0, 0);
    }
    if (t > 0) {  // wait for all WGs to have published h row t
      const u32 target = (u32)t;
      while (true) {
        u32 m0 = ldflag(flags + (size_t)l * 32);
        u32 m1 = ldflag(flags + (size_t)(l + 64) * 32);
        u32 m2 = ldflag(flags + (size_t)(l + 128) * 32);
        u32 m3 = ldflag(flags + (size_t)(l + 192) * 32);
        u32 mn = m0 < m1 ? m0 : m1;
        u32 mn2 = m2 < m3 ? m2 : m3;
        mn = mn < mn2 ? mn : mn2;
        if (__all((int)(mn >= target))) break;
      }
      asm volatile("" ::: "memory");
    }
#pragma unroll 8
    for (int c = 0; c < 32; ++c) {  // h @ W_hh^T  (plain cached loads, fresh row)
      bf16x8 bv = *reinterpret_cast<const bf16x8*>(hrow + boff + c * 32);
      acc = __builtin_amdgcn_mfma_f32_16x16x32_bf16(wfrag[2048 + c * 64 + l], bv, acc, 0, 0, 0);
    }
    // lane (bb, q) holds its own i,f,g,o in acc[0..3]
    float gi = acc[0] + bias_g[0];
    float gf = acc[1] + bias_g[1];
    float gg = acc[2] + bias_g[2];
    float go = acc[3] + bias_g[3];
    float si = 1.f / (1.f + __expf(-gi));
    float sf = 1.f / (1.f + __expf(-gf));
    float tg = tanhf(gg);
    float so = 1.f / (1.f + __expf(-go));
    creg = sf * creg + si * tg;
    float hval = so * tanhf(creg);

    // pack the 4 unit values of each batch row into one u64 on lanes q==0,
    // store write-through to LLC (agent scope, fresh row t+1)
    u32 pk = (u32)f2bf(hval);
    u32 x0 = pk | ((u32)__shfl_xor((int)pk, 16, 64) << 16);
    u32 y  = (u32)__shfl_xor((int)x0, 32, 64);
    if (q == 0) {
      u64 full = (u64)x0 | ((u64)y << 32);
      __hip_atomic_store(reinterpret_cast<u64*>(hbuf + (size_t)(t + 1) * (B_ * H_) + bb * H_ + p * 4),
                         full, __ATOMIC_RELAXED, __HIP_MEMORY_SCOPE_AGENT);
    }
    // span accumulation overlaps the store ack
#pragma unroll
    for (int n = 0; n < NSP; ++n)
      if (t >= hd[n] + 1 && t < tl[n]) aspan[n] += hval;

    asm volatile("s_waitcnt vmcnt(0)" ::: "memory");   // h stores acked at LLC
    if (l == 0)
      __hip_atomic_store(flags + (size_t)p * 32, (u32)(t + 1),
                         __ATOMIC_RELAXED, __HIP_MEMORY_SCOPE_AGENT);
  }
#pragma unroll
  for (int n = 0; n < NSP; ++n)
    spanacc[(size_t)(bb * NSP + n) * H_ + p * 4 + q] = aspan[n];
}

// ---------------- small GEMM: C[M,N] = A[M,K] @ Bw[N,K]^T + bias ----------------

__launch_bounds__(256, 2)
__global__ void k_gemm(const u16* __restrict__ A, const u16* __restrict__ Bw,
                       const float* __restrict__ bias, float* __restrict__ C,
                       int M, int N, int K) {
  __shared__ __align__(16) u16 As[64][40];
  __shared__ __align__(16) u16 Bs[64][40];
  const int bm = blockIdx.y * 64, bn = blockIdx.x * 64;
  const int tid = threadIdx.x;
  const int w = tid >> 6, l = tid & 63;
  const int sr = tid >> 2, sc = (tid & 3) * 8;
  f32x4 acc[4];
#pragma unroll
  for (int j = 0; j < 4; ++j) acc[j] = (f32x4){0.f, 0.f, 0.f, 0.f};
  for (int k0 = 0; k0 < K; k0 += 32) {
    *reinterpret_cast<uint4*>(&As[sr][sc]) =
        *reinterpret_cast<const uint4*>(A + (size_t)(bm + sr) * K + k0 + sc);
    *reinterpret_cast<uint4*>(&Bs[sr][sc]) =
        *reinterpret_cast<const uint4*>(Bw + (size_t)(bn + sr) * K + k0 + sc);
    __syncthreads();
    bf16x8 af = *reinterpret_cast<const bf16x8*>(&As[w * 16 + (l & 15)][(l >> 4) * 8]);
#pragma unroll
    for (int j = 0; j < 4; ++j) {
      bf16x8 bf_ = *reinterpret_cast<const bf16x8*>(&Bs[j * 16 + (l & 15)][(l >> 4) * 8]);
      acc[j] = __builtin_amdgcn_mfma_f32_16x16x32_bf16(af, bf_, acc[j], 0, 0, 0);
    }
    __syncthreads();
  }
#pragma unroll
  for (int j = 0; j < 4; ++j) {
    int col = bn + j * 16 + (l & 15);
    float bv = bias ? bias[col] : 0.f;
#pragma unroll
    for (int r = 0; r < 4; ++r) {
      int row = bm + w * 16 + (l >> 4) * 4 + r;
      C[(size_t)row * N + col] = acc[j][r] + bv;
    }
  }
}

// ---------------- LayerNorm kernels ----------------

DEVFN float blk_reduce(float v, float* lds) {
#pragma unroll
  for (int k = 32; k >= 1; k >>= 1) v += __shfl_xor(v, k, 64);
  __syncthreads();
  if ((threadIdx.x & 63) == 0) lds[threadIdx.x >> 6] = v;
  __syncthreads();
  return lds[0] + lds[1] + lds[2] + lds[3];
}

__global__ void k_ln1(const float* __restrict__ acc, const int* __restrict__ head,
                      const int* __restrict__ tail, const float* __restrict__ g,
                      const float* __restrict__ bta, float* __restrict__ xo,
                      u16* __restrict__ xb) {
  __shared__ float lds[4];
  int m = blockIdx.x, tid = threadIdx.x;
  int hd = head[m], tl = tail[m];
  int lo = hd + 1 > 0 ? hd + 1 : 0;
  int hi = tl < S_ ? tl : S_;
  float cnt = (float)(hi - lo > 0 ? hi - lo : 0);
  if (cnt < 1.f) cnt = 1.f;
  float inv = 1.f / cnt;
  float4 v = reinterpret_cast<const float4*>(acc + (size_t)m * H_)[tid];
  v.x *= inv; v.y *= inv; v.z *= inv; v.w *= inv;
  float s = blk_reduce(v.x + v.y + v.z + v.w, lds);
  float mean = s * (1.f / H_);
  float dx = v.x - mean, dy = v.y - mean, dz = v.z - mean, dw = v.w - mean;
  float ss = blk_reduce(dx * dx + dy * dy + dz * dz + dw * dw, lds);
  float rstd = 1.f / sqrtf(ss * (1.f / H_) + 1e-7f);
  int k = tid * 4;
  float o0 = dx * rstd * g[k + 0] + bta[k + 0];
  float o1 = dy * rstd * g[k + 1] + bta[k + 1];
  float o2 = dz * rstd * g[k + 2] + bta[k + 2];
  float o3 = dw * rstd * g[k + 3] + bta[k + 3];
  float4 ov = {o0, o1, o2, o3};
  reinterpret_cast<float4*>(xo + (size_t)m * H_)[tid] = ov;
  ushort4 ob;
  ob.x = f2bf(o0); ob.y = f2bf(o1); ob.z = f2bf(o2); ob.w = f2bf(o3);
  reinterpret_cast<ushort4*>(xb + (size_t)m * H_)[tid] = ob;
}

__global__ void k_ln2(const float* __restrict__ oo, const float* __restrict__ xres,
                      const float* __restrict__ g, const float* __restrict__ bta,
                      u16* __restrict__ ao) {
  __shared__ float lds[4];
  int m = blockIdx.x, tid = threadIdx.x;
  float4 a = reinterpret_cast<const float4*>(oo + (size_t)m * H_)[tid];
  float4 r = reinterpret_cast<const float4*>(xres + (size_t)m * H_)[tid];
  float4 v = {a.x + r.x, a.y + r.y, a.z + r.z, a.w + r.w};
  float s = blk_reduce(v.x + v.y + v.z + v.w, lds);
  float mean = s * (1.f / H_);
  float dx = v.x - mean, dy = v.y - mean, dz = v.z - mean, dw = v.w - mean;
  float ss = blk_reduce(dx * dx + dy * dy + dz * dz + dw * dw, lds);
  float rstd = 1.f / sqrtf(ss * (1.f / H_) + 1e-7f);
  int k = tid * 4;
  ushort4 ob;
  ob.x = f2bf(dx * rstd * g[k + 0] + bta[k + 0]);
  ob.y = f2bf(dy * rstd * g[k + 1] + bta[k + 1]);
  ob.z = f2bf(dz * rstd * g[k + 2] + bta[k + 2]);
  ob.w = f2bf(dw * rstd * g[k + 3] + bta[k + 3]);
  reinterpret_cast<ushort4*>(ao + (size_t)m * H_)[tid] = ob;
}

// ---------------- attention over spans (32x32 per (b,head)) ----------------

__launch_bounds__(256, 2)
__global__ void k_attn(const float* __restrict__ qf, const float* __restrict__ kf,
                       const float* __restrict__ vf, const int* __restrict__ am,
                       u16* __restrict__ ctx) {
  __shared__ float qs[32][65], ks[32][65], vs[32][65];
  __shared__ float ps[32][33];
  __shared__ int msk[32];
  int blk = blockIdx.x;
  int b = blk >> 4, hh = blk & 15;
  int tid = threadIdx.x;
  for (int i = tid; i < 32 * 64; i += 256) {
    int n = i >> 6, d = i & 63;
    size_t src = (size_t)(b * 32 + n) * H_ + hh * 64 + d;
    qs[n][d] = qf[src];
    ks[n][d] = kf[src];
    vs[n][d] = vf[src];
  }
  if (tid < 32) msk[tid] = am[b * 32 + tid];
  __syncthreads();
  for (int pr = tid; pr < 1024; pr += 256) {
    int i = pr >> 5, j = pr & 31;
    float s = 0.f;
#pragma unroll
    for (int d = 0; d < 64; ++d) s += qs[i][d] * ks[j][d];
    s *= 0.125f;
    if (!(msk[i] && msk[j])) s = -3.402823466e38f;
    ps[i][j] = s;
  }
  __syncthreads();
  if (tid < 32) {
    int i = tid;
    float mx = -3.402823466e38f;
#pragma unroll
    for (int j = 0; j < 32; ++j) mx = fmaxf(mx, ps[i][j]);
    float e[32];
    float sum = 0.f;
#pragma unroll
    for (int j = 0; j < 32; ++j) {
      e[j] = __expf(ps[i][j] - mx);
      sum += e[j];
    }
    float invs = 1.f / sum;
#pragma unroll
    for (int j = 0; j < 32; ++j) ps[i][j] = e[j] * invs;
  }
  __syncthreads();
  for (int o = tid; o < 32 * 64; o += 256) {
    int i = o >> 6, d = o & 63;
    float s = 0.f;
#pragma unroll
    for (int j = 0; j < 32; ++j) s += ps[i][j] * vs[j][d];
    ctx[(size_t)(b * 32 + i) * H_ + hh * 64 + d] = f2bf(s);
  }
}

// ---------------- classifier head ----------------

__global__ void k_cls(const u16* __restrict__ ao, const float* __restrict__ Wc,
                      const float* __restrict__ bc, float* __restrict__ out) {
  int m = blockIdx.x, lane = threadIdx.x;
#pragma unroll
  for (int c = 0; c < 3; ++c) {
    float s = 0.f;
    for (int k = lane; k < H_; k += 64) s += bf2f(ao[(size_t)m * H_ + k]) * Wc[c * H_ + k];
#pragma unroll
    for (int k = 32; k >= 1; k >>= 1) s += __shfl_xor(s, k, 64);
    if (lane == 0) out[m * 3 + c] = s + bc[c];
  }
}

// ---------------- host launcher ----------------

extern "C" void kernel_launch(void* const* d_in, const int* in_sizes, int n_in,
                              void* d_out, int out_size, void* d_ws, size_t ws_size,
                              hipStream_t stream) {
  const float* x = (const float*)d_in[0];
  const int* head = (const int*)d_in[1];
  const int* tail = (const int*)d_in[2];
  const int* amask = (const int*)d_in[3];
  const float* Wih = (const float*)d_in[4];
  const float* Whh = (const float*)d_in[5];
  const float* bih = (const float*)d_in[6];
  const float* bhh = (const float*)d_in[7];
  const float* lng = (const float*)d_in[8];
  const float* lnb = (const float*)d_in[9];
  const float* Wq = (const float*)d_in[10];
  const float* bq = (const float*)d_in[11];
  const float* Wk = (const float*)d_in[12];
  const float* bk = (const float*)d_in[13];
  const float* Wv = (const float*)d_in[14];
  const float* bv = (const float*)d_in[15];
  const float* Wo = (const float*)d_in[16];
  const float* bo = (const float*)d_in[17];
  const float* ln2g = (const float*)d_in[18];
  const float* ln2b = (const float*)d_in[19];
  const float* Wc = (const float*)d_in[20];
  const float* bc = (const float*)d_in[21];
  float* out = (float*)d_out;

  char* wsb = (char*)d_ws;
  size_t off = 0;
  auto alloc = [&](size_t bytes) -> void* {
    void* pp = wsb + off;
    off = (off + bytes + 255) & ~(size_t)255;
    return pp;
  };
  u16* xT = (u16*)alloc((size_t)S_ * B_ * H_ * 2);          // 32 MB
  u16* Wpk = (u16*)alloc((size_t)NWG * 32768 * 2);          // 16 MB
  u16* Wqb = (u16*)alloc((size_t)H_ * H_ * 2);
  u16* Wkb = (u16*)alloc((size_t)H_ * H_ * 2);
  u16* Wvb = (u16*)alloc((size_t)H_ * H_ * 2);
  u16* Wob = (u16*)alloc((size_t)H_ * H_ * 2);
  float* bias4 = (float*)alloc((size_t)G4 * 4);
  u16* hbuf = (u16*)alloc((size_t)(S_ + 1) * B_ * H_ * 2);  // 32.8 MB full history
  u32* flags = (u32*)alloc((size_t)NWG * 32 * 4);           // 128B-spaced per-WG flags
  float* spanacc = (float*)alloc((size_t)B_ * NSP * H_ * 4);
  float* xo = (float*)alloc((size_t)512 * H_ * 4);
  u16* xb = (u16*)alloc((size_t)512 * H_ * 2);
  float* qf = (float*)alloc((size_t)512 * H_ * 4);
  float* kf = (float*)alloc((size_t)512 * H_ * 4);
  float* vf = (float*)alloc((size_t)512 * H_ * 4);
  u16* ctx = (u16*)alloc((size_t)512 * H_ * 2);
  float* oo = (float*)alloc((size_t)512 * H_ * 4);
  u16* ao = (u16*)alloc((size_t)512 * H_ * 2);
  (void)ws_size; (void)in_sizes; (void)n_in; (void)out_size;

  hipMemsetAsync(flags, 0, (size_t)NWG * 32 * 4, stream);
  hipMemsetAsync(hbuf, 0, (size_t)B_ * H_ * 2, stream);     // h row 0 = zeros

  k_prep_x<<<16384, 256, 0, stream>>>(x, xT);
  k_prep_small<<<16400, 256, 0, stream>>>(Wq, Wk, Wv, Wo, Wqb, Wkb, Wvb, Wob, bih, bhh, bias4);
  k_prep_wpack<<<4096, 256, 0, stream>>>(Wih, Whh, Wpk);

  k_lstm<<<NWG, 64, 0, stream>>>(xT, Wpk, bias4, head, tail, hbuf, flags, spanacc);

  k_ln1<<<512, 256, 0, stream>>>(spanacc, head, tail, lng, lnb, xo, xb);
  dim3 g1(16, 8);
  k_gemm<<<g1, 256, 0, stream>>>(xb, Wqb, bq, qf, 512, H_, H_);
  k_gemm<<<g1, 256, 0, stream>>>(xb, Wkb, bk, kf, 512, H_, H_);
  k_gemm<<<g1, 256, 0, stream>>>(xb, Wvb, bv, vf, 512, H_, H_);
  k_attn<<<256, 256, 0, stream>>>(qf, kf, vf, amask, ctx);
  k_gemm<<<g1, 256, 0, stream>>>(ctx, Wob, bo, oo, 512, H_, H_);
  k_ln2<<<512, 256, 0, stream>>>(oo, xo, ln2g, ln2b, ao);
  k_cls<<<512, 64, 0, stream>>>(ao, Wc, bc, out);
}